// Round 2
// baseline (721.311 us; speedup 1.0000x reference)
//
#include <hip/hip_runtime.h>

// VoxelHashTableFlowTraverse: 8-corner hash-grid lookup + trilinear blend.
// Layout: 32 lanes per query; lane c owns float4 chunk c of the 120-float
// feature row (lanes 30,31 duplicate chunk 29 for loads, masked on store).
// All 8 table probes then all 8 feature gathers issued independently for
// max memory-level parallelism. Output stored non-temporally so the 480MB
// write stream doesn't evict the 137MB feature table from Infinity Cache.

#define TABLE_MASK ((1u << 20) - 1u)
#define FEAT_DIM 120

typedef float f4 __attribute__((ext_vector_type(4)));

__global__ __launch_bounds__(256) void voxel_trilinear_kernel(
    const float* __restrict__ qp,      // [M,3]
    const float* __restrict__ feat,    // [n_vox,120]
    const int*   __restrict__ table,   // [2^20]
    float*       __restrict__ out,     // [M,120]
    int M)
{
    const int gid = blockIdx.x * blockDim.x + threadIdx.x;
    const int q = gid >> 5;        // query index
    const int c = gid & 31;        // float4 chunk index within feature row
    if (q >= M) return;
    const int ce = (c < 30) ? c : 29;   // clamp: lanes 30/31 re-read chunk 29

    // Query point (broadcast load within the 32-lane group)
    const float px = qp[q * 3 + 0];
    const float py = qp[q * 3 + 1];
    const float pz = qp[q * 3 + 2];

    // Must divide by 0.1f (not multiply by 10) to match reference rounding.
    const float gx = px / 0.1f;
    const float gy = py / 0.1f;
    const float gz = pz / 0.1f;
    const float flx = floorf(gx), fly = floorf(gy), flz = floorf(gz);
    const float rx = gx - flx, ry = gy - fly, rz = gz - flz;
    const int bx = (int)flx, by = (int)fly, bz = (int)flz;

    // Hash components (wrapping uint32 arithmetic, masked to 20 bits).
    const unsigned hx0 = (unsigned)bx * 73856093u;
    const unsigned hy0 = (unsigned)by * 19349669u;
    const unsigned hz0 = (unsigned)bz * 83492791u;
    const unsigned hx1 = hx0 + 73856093u;
    const unsigned hy1 = hy0 + 19349669u;
    const unsigned hz1 = hz0 + 83492791u;

    // Corner order matches reference:
    // (0,0,0),(1,0,0),(0,1,0),(0,0,1),(1,1,0),(1,0,1),(0,1,1),(1,1,1)
    unsigned h[8];
    h[0] = (hx0 + hy0 + hz0) & TABLE_MASK;
    h[1] = (hx1 + hy0 + hz0) & TABLE_MASK;
    h[2] = (hx0 + hy1 + hz0) & TABLE_MASK;
    h[3] = (hx0 + hy0 + hz1) & TABLE_MASK;
    h[4] = (hx1 + hy1 + hz0) & TABLE_MASK;
    h[5] = (hx1 + hy0 + hz1) & TABLE_MASK;
    h[6] = (hx0 + hy1 + hz1) & TABLE_MASK;
    h[7] = (hx1 + hy1 + hz1) & TABLE_MASK;

    // All 8 table probes in flight simultaneously.
    int vidx[8];
#pragma unroll
    for (int k = 0; k < 8; ++k) vidx[k] = table[h[k]];

    // Trilinear weights, same corner order.
    const float sx = 1.0f - rx, sy = 1.0f - ry, sz = 1.0f - rz;
    float w[8];
    w[0] = sx * sy * sz;
    w[1] = rx * sy * sz;
    w[2] = sx * ry * sz;
    w[3] = sx * sy * rz;
    w[4] = rx * ry * sz;
    w[5] = rx * sy * rz;
    w[6] = sx * ry * rz;
    w[7] = rx * ry * rz;

    // All 8 feature gathers issued branchlessly (row 0 with weight 0 for
    // empty slots — identical to reference's features[max(vidx,0)] * 0).
    f4 acc = (f4)(0.0f);
#pragma unroll
    for (int k = 0; k < 8; ++k) {
        const int v = vidx[k] >= 0 ? vidx[k] : 0;
        const float wk = vidx[k] >= 0 ? w[k] : 0.0f;
        const f4 f = *reinterpret_cast<const f4*>(
            feat + (size_t)v * FEAT_DIM + ce * 4);
        acc += f * wk;
    }

    if (c < 30) {
        __builtin_nontemporal_store(
            acc, reinterpret_cast<f4*>(out + (size_t)q * FEAT_DIM + c * 4));
    }
}

extern "C" void kernel_launch(void* const* d_in, const int* in_sizes, int n_in,
                              void* d_out, int out_size, void* d_ws, size_t ws_size,
                              hipStream_t stream) {
    const float* qp    = (const float*)d_in[0];
    const float* feat  = (const float*)d_in[1];
    const int*   table = (const int*)d_in[2];
    float*       out   = (float*)d_out;

    const int M = in_sizes[0] / 3;                  // number of queries
    const long long threads = (long long)M * 32;    // 32 lanes per query
    const int block = 256;
    const int grid = (int)((threads + block - 1) / block);

    voxel_trilinear_kernel<<<grid, block, 0, stream>>>(qp, feat, table, out, M);
}